// Round 11
// baseline (224.867 us; speedup 1.0000x reference)
//
#include <hip/hip_runtime.h>

typedef unsigned short u16;
using short8  = __attribute__((ext_vector_type(8))) short;
using float4v = __attribute__((ext_vector_type(4))) float;

__device__ __forceinline__ u16 f2bf(float f) {
    union { float f; unsigned u; } v; v.f = f;
    unsigned r = (v.u + 0x7fff + ((v.u >> 16) & 1)) >> 16;
    return (u16)r;
}
__device__ __forceinline__ float bf2f(u16 h) {
    union { unsigned u; float f; } v; v.u = ((unsigned)h) << 16; return v.f;
}
// HW packed f32x2 -> bf16x2 (lo in low 16 bits). CDNA3+/gfx950.
__device__ __forceinline__ unsigned pkbf(float lo, float hi) {
    unsigned d;
    asm("v_cvt_pk_bf16_f32 %0, %1, %2" : "=v"(d) : "v"(lo), "v"(hi));
    return d;
}
// sin(2*pi*r): v_fract then hardware v_sin (input in revolutions).
__device__ __forceinline__ float sin_rev(float r) {
    float f, s;
    asm("v_fract_f32 %0, %1" : "=v"(f) : "v"(r));
    asm("v_sin_f32 %0, %1" : "=v"(s) : "v"(f));
    return s;
}
__device__ __forceinline__ void dma16(const void* g, void* l) {
    __builtin_amdgcn_global_load_lds((const __attribute__((address_space(1))) void*)g,
                                     (__attribute__((address_space(3))) void*)l, 16, 0, 0);
}

__constant__ float c_inv_em[8] = {1.0f, 0.4216965034f, 0.1778279410f, 0.0749894209f,
                                  0.0316227766f, 0.0133352143f, 0.0056234133f, 0.0023713737f};
#define REVC 15.91549431f  /* 100 / (2*pi) */

// ---------------------------------------------------------------------------
// merged f32 -> bf16 bulk convert for five tensors + PD1/PD2 precompute
// PD1[p] = (pcx, pcy)   (float2)
// PD2[p][32] (bf16) = [sin(phi_w k)]x8 [cos(phi_w k)]x8 [sin(phi_h k)]x8
//                     [cos(phi_h k)]x8, phi = REV*inv_em[k]*log(pw or ph)
// ---------------------------------------------------------------------------
__device__ __forceinline__ void cvt4(const float* __restrict__ s, u16* __restrict__ o, int i) {
    float4 v = ((const float4*)s)[i];
    uint2 r; r.x = pkbf(v.x, v.y); r.y = pkbf(v.z, v.w);
    ((uint2*)o)[i] = r;
}

__global__ __launch_bounds__(256)
void cvt_all(const float* __restrict__ s0, const float* __restrict__ s1,
             const float* __restrict__ s2, const float* __restrict__ s3,
             const float* __restrict__ s4, const float* __restrict__ prois,
             u16* __restrict__ o0, u16* __restrict__ o1, u16* __restrict__ o2,
             u16* __restrict__ o3, u16* __restrict__ o4,
             float2* __restrict__ PD1, u16* __restrict__ PD2,
             int na4, int nb4, int nw4, int PT) {
    int i = blockIdx.x * 256 + threadIdx.x;
    if (i < na4) { cvt4(s0, o0, i); return; }
    i -= na4;
    if (i < nb4) { cvt4(s1, o1, i); return; }
    i -= nb4;
    if (i < nw4) { cvt4(s2, o2, i); return; }
    i -= nw4;
    if (i < nw4) { cvt4(s3, o3, i); return; }
    i -= nw4;
    if (i < nw4) { cvt4(s4, o4, i); return; }
    i -= nw4;
    if (i < PT) {
        const float* pr = prois + (size_t)i * 5;
        float pxmin = pr[1], pymin = pr[2], pxmax = pr[3], pymax = pr[4];
        PD1[i] = make_float2(0.5f * (pxmin + pxmax), 0.5f * (pymin + pymax));
        float lpw = __logf(pxmax - pxmin + 1.0f);
        float lph = __logf(pymax - pymin + 1.0f);
        u16 out[32];
#pragma unroll
        for (int k = 0; k < 8; ++k) {
            float pw_ = REVC * c_inv_em[k] * lpw;
            float ph_ = REVC * c_inv_em[k] * lph;
            out[k]      = f2bf(sin_rev(pw_));
            out[8 + k]  = f2bf(sin_rev(pw_ + 0.25f));
            out[16 + k] = f2bf(sin_rev(ph_));
            out[24 + k] = f2bf(sin_rev(ph_ + 0.25f));
        }
        u16* dst = PD2 + (size_t)i * 32;
#pragma unroll
        for (int q = 0; q < 4; ++q)
            *(ushort4*)(dst + q * 8 + 0) = make_ushort4(out[q*8], out[q*8+1], out[q*8+2], out[q*8+3]),
            *(ushort4*)(dst + q * 8 + 4) = make_ushort4(out[q*8+4], out[q*8+5], out[q*8+6], out[q*8+7]);
    }
}

// ---------------------------------------------------------------------------
// proj: C[m,j] = sum_k A[m,k]*W[j,k] (+bias). z=0: Q, z=1: K, z=2: PV->PVt.
// Tile 128m x 64j, BK=64, grid (16j,16m,3) = 768 blocks (3/CU).
// ---------------------------------------------------------------------------
__global__ __launch_bounds__(256)
void proj_mfma(const u16* __restrict__ Ab, const u16* __restrict__ Pb,
               const u16* __restrict__ Wqb, const u16* __restrict__ Wkb,
               const u16* __restrict__ Cwb, const float* __restrict__ bq,
               const float* __restrict__ bk, u16* __restrict__ Qb,
               u16* __restrict__ Kb, u16* __restrict__ PVt, int PT) {
    __shared__ __align__(16) u16 As[128 * 64];
    __shared__ __align__(16) u16 Ws[64 * 64];
    __shared__ __align__(16) u16 Tr[128 * 68];

    const int z = blockIdx.z;
    const int m0 = blockIdx.y * 128, j0 = blockIdx.x * 64;
    const u16* A = (z == 0) ? Ab : Pb;
    const u16* W = (z == 0) ? Wqb : (z == 1 ? Wkb : Cwb);
    const int t = threadIdx.x;
    const int w = t >> 6, lane = t & 63;
    const int wm = w >> 1, wn = w & 1;
    const int lr = lane >> 3, lc = lane & 7, gch = lc ^ lr;
    const int fm = lane & 15, quad = lane >> 4;

    float4v zero4 = {0.f, 0.f, 0.f, 0.f};
    float4v acc[4][2];
#pragma unroll
    for (int i = 0; i < 4; ++i) { acc[i][0] = zero4; acc[i][1] = zero4; }

    for (int k0 = 0; k0 < 1024; k0 += 64) {
#pragma unroll
        for (int i = 0; i < 4; ++i) {
            int row = w * 32 + i * 8 + lr;
            dma16(A + (size_t)(m0 + row) * 1024 + k0 + gch * 8,
                  As + (w * 32 + i * 8) * 64 + lane * 8);
        }
#pragma unroll
        for (int i = 0; i < 2; ++i) {
            int row = w * 16 + i * 8 + lr;
            dma16(W + (size_t)(j0 + row) * 1024 + k0 + gch * 8,
                  Ws + (w * 16 + i * 8) * 64 + lane * 8);
        }
        __syncthreads();
#pragma unroll
        for (int ks = 0; ks < 2; ++ks) {
            int c = ks * 4 + quad;
            short8 af[4], bf[2];
#pragma unroll
            for (int i = 0; i < 4; ++i) {
                int ra = wm * 64 + i * 16 + fm;
                af[i] = *(const short8*)(As + ra * 64 + ((c ^ (ra & 7)) * 8));
            }
#pragma unroll
            for (int j = 0; j < 2; ++j) {
                int rb = wn * 32 + j * 16 + fm;
                bf[j] = *(const short8*)(Ws + rb * 64 + ((c ^ (rb & 7)) * 8));
            }
#pragma unroll
            for (int i = 0; i < 4; ++i)
#pragma unroll
                for (int j = 0; j < 2; ++j)
                    acc[i][j] = __builtin_amdgcn_mfma_f32_16x16x32_bf16(af[i], bf[j], acc[i][j], 0, 0, 0);
        }
        __syncthreads();
    }

    if (z < 2) {
        u16* O = z ? Kb : Qb;
        const float* bias = z ? bk : bq;
#pragma unroll
        for (int j = 0; j < 2; ++j) {
            int jl = wn * 32 + j * 16 + fm;
            float bb = bias[j0 + jl];
#pragma unroll
            for (int i = 0; i < 4; ++i) {
                int mlb = wm * 64 + i * 16 + quad * 4;
#pragma unroll
                for (int r = 0; r < 4; ++r)
                    Tr[(mlb + r) * 68 + jl] = f2bf(acc[i][j][r] + bb);
            }
        }
        __syncthreads();
#pragma unroll
        for (int i2 = 0; i2 < 4; ++i2) {
            int f = i2 * 2048 + t * 8;
            int ml = f >> 6, jl = f & 63;
            union { uint2 u2[2]; short8 s8; } uu;
            uu.u2[0] = *(const uint2*)(Tr + ml * 68 + jl);
            uu.u2[1] = *(const uint2*)(Tr + ml * 68 + jl + 4);
            *(short8*)(O + (size_t)(m0 + ml) * 1024 + j0 + jl) = uu.s8;
        }
    } else {
#pragma unroll
        for (int j = 0; j < 2; ++j) {
            int jl = wn * 32 + j * 16 + fm;
#pragma unroll
            for (int i = 0; i < 4; ++i) {
                int mlb = wm * 64 + i * 16 + quad * 4;
                uint2 pk;
                pk.x = pkbf(acc[i][j][0], acc[i][j][1]);
                pk.y = pkbf(acc[i][j][2], acc[i][j][3]);
                *(uint2*)(Tr + jl * 136 + mlb) = pk;
            }
        }
        __syncthreads();
#pragma unroll
        for (int i2 = 0; i2 < 4; ++i2) {
            int f = i2 * 2048 + t * 8;
            int jl = f >> 7, ml = f & 127;
            union { uint2 u2[2]; short8 s8; } uu;
            uu.u2[0] = *(const uint2*)(Tr + jl * 136 + ml);
            uu.u2[1] = *(const uint2*)(Tr + jl * 136 + ml + 4);
            *(short8*)(PVt + (size_t)(j0 + jl) * PT + m0 + ml) = uu.s8;
        }
    }
}

// ---------------------------------------------------------------------------
// att: ATT[n][g][p] = exp((1/16) sum_d Q*K)  -- exp folded in, bf16 out.
// ---------------------------------------------------------------------------
__global__ __launch_bounds__(256)
void att_mfma(const u16* __restrict__ Qb, const u16* __restrict__ Kb,
              u16* __restrict__ ATT, const int* __restrict__ n1b_p,
              const int* __restrict__ n1p_p, int PT) {
    __shared__ __align__(16) u16 Qs[128 * 64];
    __shared__ __align__(16) u16 Ks[128 * 64];
    __shared__ __align__(16) u16 Tr[128 * 130];

    const int g = blockIdx.z;
    const int n0 = blockIdx.y * 128, pl0 = blockIdx.x * 128;
    const int n1b = *n1b_p, n1p = *n1p_p;
    const int hh = (n0 >= n1b) ? 1 : 0;
    const int p0 = hh ? n1p : 0;
    const int Ph = hh ? (PT - n1p) : n1p;
    if (pl0 >= Ph) return;
    const int t = threadIdx.x;
    const int w = t >> 6, lane = t & 63;
    const int wm = w >> 1, wn = w & 1;
    const int lr = lane >> 3, lc = lane & 7, gch = lc ^ lr;
    const int fm = lane & 15, quad = lane >> 4;

    float4v zero4 = {0.f, 0.f, 0.f, 0.f};
    float4v acc[4][4];
#pragma unroll
    for (int i = 0; i < 4; ++i)
#pragma unroll
        for (int j = 0; j < 4; ++j) acc[i][j] = zero4;

#pragma unroll
    for (int i = 0; i < 4; ++i) {
        int row = w * 32 + i * 8 + lr;
        dma16(Qb + (size_t)(n0 + row) * 1024 + g * 64 + gch * 8,
              Qs + (w * 32 + i * 8) * 64 + lane * 8);
        dma16(Kb + (size_t)(p0 + pl0 + row) * 1024 + g * 64 + gch * 8,
              Ks + (w * 32 + i * 8) * 64 + lane * 8);
    }
    __syncthreads();
#pragma unroll
    for (int ks = 0; ks < 2; ++ks) {
        int c = ks * 4 + quad;
        short8 af[4], bf[4];
#pragma unroll
        for (int i = 0; i < 4; ++i) {
            int ra = wm * 64 + i * 16 + fm;
            af[i] = *(const short8*)(Qs + ra * 64 + ((c ^ (ra & 7)) * 8));
            int rb = wn * 64 + i * 16 + fm;
            bf[i] = *(const short8*)(Ks + rb * 64 + ((c ^ (rb & 7)) * 8));
        }
#pragma unroll
        for (int i = 0; i < 4; ++i)
#pragma unroll
            for (int j = 0; j < 4; ++j)
                acc[i][j] = __builtin_amdgcn_mfma_f32_16x16x32_bf16(af[i], bf[j], acc[i][j], 0, 0, 0);
    }
#pragma unroll
    for (int j = 0; j < 4; ++j) {
        int pl = wn * 64 + j * 16 + fm;
#pragma unroll
        for (int i = 0; i < 4; ++i)
#pragma unroll
            for (int r = 0; r < 4; ++r) {
                int nl = wm * 64 + i * 16 + quad * 4 + r;
                Tr[nl * 130 + pl] = f2bf(__expf(acc[i][j][r] * 0.0625f));
            }
    }
    __syncthreads();
#pragma unroll
    for (int i = 0; i < 8; ++i) {
        int f = i * 2048 + t * 8;
        int nl = f >> 7, pl = f & 127;
        short8 v = *(const short8*)(Tr + nl * 130 + pl);
        *(short8*)(ATT + ((size_t)(n0 + nl) * 16 + g) * 1024 + pl0 + pl) = v;
    }
}

// ---------------------------------------------------------------------------
// softmax: w[n,g,p] = max(pf,1e-6)*eatt, UNNORMALIZED, in-place in ATT (direct
// global RMW in D-layout). All 16 eatt loads hoisted to registers up front
// (one pipelined latency instead of 16 serial ones). dw/dh half of the pos
// MFMA uses the angle-difference identity (PD2 table + rotated B-fragment);
// only dx/dy needs in-loop trig (8 sins). INV[n][g] = 1/sum_p w.
// ---------------------------------------------------------------------------
__global__ __launch_bounds__(256)
void softmax_fused(const float* __restrict__ rois, const float2* __restrict__ PD1,
                   const u16* __restrict__ PD2,
                   const float* __restrict__ Wg_w, const float* __restrict__ Wg_b,
                   u16* __restrict__ ATT, float* __restrict__ INV,
                   const int* __restrict__ n1b_p, const int* __restrict__ n1p_p, int PT) {
    __shared__ float redl[4][16];

    const int n = blockIdx.x, t = threadIdx.x;
    const int w = t >> 6, lane = t & 63;
    const int fm = lane & 15, quad = lane >> 4;
    const int n1b = *n1b_p, n1p = *n1p_p;
    const int hh = (n >= n1b) ? 1 : 0;
    const int p0 = hh ? n1p : 0;
    const int Ph = hh ? (PT - n1p) : n1p;   // 1024

    const int prange = Ph >> 2;      // p per wave (256)
    const int pb0 = w * prange;
    const int g_ = fm;
    u16* rowp = ATT + ((size_t)n * 16 + g_) * 1024;  // row for g = fm

    // ---- preload ALL 16 eatt chunks (pipelined; breaks the serial chain) ----
    ushort4 ea[16];
#pragma unroll
    for (int pt = 0; pt < 16; ++pt)
        ea[pt] = *(const ushort4*)(rowp + pb0 + pt * 16 + quad * 4);

    // n-box (block-uniform)
    float xmin = rois[n * 5 + 1], ymin = rois[n * 5 + 2];
    float xmax = rois[n * 5 + 3], ymax = rois[n * 5 + 4];
    float bw = xmax - xmin + 1.0f, bh = ymax - ymin + 1.0f;
    float cx = 0.5f * (xmin + xmax), cy = 0.5f * (ymin + ymax);

    const int sel = quad >> 1, which = quad & 1;
    float cA   = sel ? cy : cx;
    float invA = sel ? (1.0f / bh) : (1.0f / bw);
    float lB   = sel ? __logf(bh) : __logf(bw);
    float toff = which ? 0.25f : 0.0f;

    // b1: dx/dy weights, unrotated (in-loop trig path)
    short8 b1;
    {
        const float* w1 = Wg_w + g_ * 64 + quad * 8;
        unsigned* p1 = (unsigned*)&b1;
#pragma unroll
        for (int kk = 0; kk < 4; ++kk)
            p1[kk] = pkbf(w1[2 * kk], w1[2 * kk + 1]);
    }
    // b2: dw/dh weights ROTATED by the n-side angle psi_k = REV*inv_em[k]*lB
    short8 b2;
    {
        const float* ws_ = Wg_w + g_ * 64 + 32 + sel * 16;   // sin weights
        const float* wc_ = ws_ + 8;                           // cos weights
        float vb[8];
#pragma unroll
        for (int k = 0; k < 8; ++k) {
            float psi = REVC * c_inv_em[k] * lB;
            float s = sin_rev(psi), c = sin_rev(psi + 0.25f);
            float a = ws_[k], b = wc_[k];
            vb[k] = which ? (b * c - a * s) : (a * c + b * s);
        }
        unsigned* p2 = (unsigned*)&b2;
#pragma unroll
        for (int kk = 0; kk < 4; ++kk)
            p2[kk] = pkbf(vb[2 * kk], vb[2 * kk + 1]);
    }
    float wgb = Wg_b[g_];

    const float REV = REVC;
    float ssum = 0.0f;

    // software pipeline for the small L2-hot tables
    float   pc_c = ((const float*)PD1)[(size_t)(p0 + pb0 + fm) * 2 + sel];
    short8  a2_c = *(const short8*)(PD2 + (size_t)(p0 + pb0 + fm) * 32 + quad * 8);

#pragma unroll 2
    for (int pt = 0; pt < 16; ++pt) {
        int pbase = pb0 + pt * 16;
        float pc_n; short8 a2_n;
        if (pt < 15) {
            pc_n = ((const float*)PD1)[(size_t)(p0 + pbase + 16 + fm) * 2 + sel];
            a2_n = *(const short8*)(PD2 + (size_t)(p0 + pbase + 16 + fm) * 32 + quad * 8);
        }
        float posA = __logf(fmaxf(fabsf(cA - pc_c) * invA, 0.001f));
        float br1 = posA * REV;
        float e1[8];
#pragma unroll
        for (int k = 0; k < 8; ++k)
            e1[k] = sin_rev(fmaf(br1, c_inv_em[k], toff));
        short8 a1;
        unsigned* pa1 = (unsigned*)&a1;
#pragma unroll
        for (int kk = 0; kk < 4; ++kk)
            pa1[kk] = pkbf(e1[2 * kk], e1[2 * kk + 1]);

        float4v acc = {wgb, wgb, wgb, wgb};
        acc = __builtin_amdgcn_mfma_f32_16x16x32_bf16(a1, b1, acc, 0, 0, 0);
        acc = __builtin_amdgcn_mfma_f32_16x16x32_bf16(a2_c, b2, acc, 0, 0, 0);

        float w0  = fmaxf(acc[0], 1e-6f) * bf2f(ea[pt].x);
        float w1v = fmaxf(acc[1], 1e-6f) * bf2f(ea[pt].y);
        float w2v = fmaxf(acc[2], 1e-6f) * bf2f(ea[pt].z);
        float w3v = fmaxf(acc[3], 1e-6f) * bf2f(ea[pt].w);
        ssum += (w0 + w1v) + (w2v + w3v);
        uint2 wp; wp.x = pkbf(w0, w1v); wp.y = pkbf(w2v, w3v);
        *(uint2*)(rowp + pbase + quad * 4) = wp;

        pc_c = pc_n; a2_c = a2_n;
    }

    ssum += __shfl_xor(ssum, 16, 64);
    ssum += __shfl_xor(ssum, 32, 64);
    if (lane < 16) redl[w][lane] = ssum;
    __syncthreads();
    if (t < 16)
        INV[(size_t)n * 16 + t] = 1.0f / (redl[0][t] + redl[1][t] + redl[2][t] + redl[3][t]);
}

// ---------------------------------------------------------------------------
// rel: OUT[n, g*64+o] = (sum_p w[n,g,p]*PVt[g*64+o, p0+p]) * INV[n,g] + conv_b
// Tile 64n x 64o, grid (NT/64, 16) = 512 blocks (2/CU).
// ---------------------------------------------------------------------------
__global__ __launch_bounds__(256)
void rel_mfma(const u16* __restrict__ SM, const u16* __restrict__ PVt,
              const float* __restrict__ conv_b, const float* __restrict__ INV,
              float* __restrict__ OUT, const int* __restrict__ n1b_p,
              const int* __restrict__ n1p_p, int PT) {
    __shared__ __align__(16) u16 As[64 * 64];
    __shared__ __align__(16) u16 Bs[64 * 64];

    const int n0 = blockIdx.x * 64, g = blockIdx.y;
    const int n1b = *n1b_p, n1p = *n1p_p;
    const int hh = (n0 >= n1b) ? 1 : 0;
    const int p0 = hh ? n1p : 0;
    const int Ph = hh ? (PT - n1p) : n1p;
    const int t = threadIdx.x;
    const int w = t >> 6, lane = t & 63;
    const int wm = w >> 1, wn = w & 1;
    const int lr = lane >> 3, lc = lane & 7, gch = lc ^ lr;
    const int fm = lane & 15, quad = lane >> 4;

    float4v zero4 = {0.f, 0.f, 0.f, 0.f};
    float4v acc[2][2];
#pragma unroll
    for (int i = 0; i < 2; ++i) { acc[i][0] = zero4; acc[i][1] = zero4; }

    for (int k0 = 0; k0 < Ph; k0 += 64) {
#pragma unroll
        for (int i = 0; i < 2; ++i) {
            int row = w * 16 + i * 8 + lr;
            dma16(SM + ((size_t)(n0 + row) * 16 + g) * 1024 + k0 + gch * 8,
                  As + (w * 16 + i * 8) * 64 + lane * 8);
            dma16(PVt + (size_t)(g * 64 + row) * PT + p0 + k0 + gch * 8,
                  Bs + (w * 16 + i * 8) * 64 + lane * 8);
        }
        __syncthreads();
#pragma unroll
        for (int ks = 0; ks < 2; ++ks) {
            int c = ks * 4 + quad;
            short8 af[2], bf[2];
#pragma unroll
            for (int i = 0; i < 2; ++i) {
                int ra = wm * 32 + i * 16 + fm;
                af[i] = *(const short8*)(As + ra * 64 + ((c ^ (ra & 7)) * 8));
                int rb = wn * 32 + i * 16 + fm;
                bf[i] = *(const short8*)(Bs + rb * 64 + ((c ^ (rb & 7)) * 8));
            }
#pragma unroll
            for (int i = 0; i < 2; ++i)
#pragma unroll
                for (int j = 0; j < 2; ++j)
                    acc[i][j] = __builtin_amdgcn_mfma_f32_16x16x32_bf16(af[i], bf[j], acc[i][j], 0, 0, 0);
        }
        __syncthreads();
    }
    float bb[2];
    bb[0] = conv_b[g * 64 + wn * 32 + fm];
    bb[1] = conv_b[g * 64 + wn * 32 + 16 + fm];
#pragma unroll
    for (int i = 0; i < 2; ++i)
#pragma unroll
        for (int r = 0; r < 4; ++r) {
            int nn = n0 + wm * 32 + i * 16 + quad * 4 + r;
            float iv = INV[(size_t)nn * 16 + g];
#pragma unroll
            for (int j = 0; j < 2; ++j) {
                int o = wn * 32 + j * 16 + fm;
                OUT[(size_t)nn * 1024 + g * 64 + o] = acc[i][j][r] * iv + bb[j];
            }
        }
}

extern "C" void kernel_launch(void* const* d_in, const int* in_sizes, int n_in,
                              void* d_out, int out_size, void* d_ws, size_t ws_size,
                              hipStream_t stream) {
    const float* rois   = (const float*)d_in[0];
    const float* prois  = (const float*)d_in[1];
    const float* bfeat  = (const float*)d_in[2];
    const float* pfeat  = (const float*)d_in[3];
    const float* Wg_w   = (const float*)d_in[4];
    const float* Wg_b   = (const float*)d_in[5];
    const float* Wq_w   = (const float*)d_in[6];
    const float* Wq_b   = (const float*)d_in[7];
    const float* Wk_w   = (const float*)d_in[8];
    const float* Wk_b   = (const float*)d_in[9];
    const float* conv_w = (const float*)d_in[10];
    const float* conv_b = (const float*)d_in[11];
    const int*   n1b    = (const int*)d_in[12];
    const int*   n1p    = (const int*)d_in[13];

    const int NT = in_sizes[2] / 1024;  // 2048
    const int PT = in_sizes[3] / 1024;  // 2048

    u16* ATT = (u16*)d_ws;                          // [NT][16][1024]
    u16* Qb  = ATT + (size_t)NT * 16 * 1024;        // [NT][1024]
    u16* Kb  = Qb + (size_t)NT * 1024;              // [PT][1024]
    u16* PVt = Kb + (size_t)PT * 1024;              // [1024][PT]
    float* INVp = (float*)(PVt + (size_t)1024 * PT);   // [NT][16]
    float2* PD1 = (float2*)(INVp + (size_t)NT * 16);   // [PT]
    u16* PD2 = (u16*)(PD1 + PT);                       // [PT][32]
    u16* Ab  = ATT;                                 // aliases (consumed by proj)
    u16* Pb  = Ab + (size_t)NT * 1024;
    u16* Wqb = Pb + (size_t)PT * 1024;
    u16* Wkb = Wqb + 1024 * 1024;
    u16* Cwb = Wkb + 1024 * 1024;

    dim3 blk(256);
    int nf4 = NT * 1024 / 4, pf4 = PT * 1024 / 4, wf4 = 1024 * 1024 / 4;
    int tot = nf4 + pf4 + 3 * wf4 + PT;
    cvt_all<<<dim3((tot + 255) / 256), blk, 0, stream>>>(
        bfeat, pfeat, Wq_w, Wk_w, conv_w, prois, Ab, Pb, Wqb, Wkb, Cwb,
        PD1, PD2, nf4, pf4, wf4, PT);

    proj_mfma<<<dim3(16, NT / 128, 3), blk, 0, stream>>>(Ab, Pb, Wqb, Wkb, Cwb,
                                                         Wq_b, Wk_b, Qb, Kb, PVt, PT);
    att_mfma<<<dim3(PT / 128, NT / 128, 16), blk, 0, stream>>>(Qb, Kb, ATT, n1b, n1p, PT);
    softmax_fused<<<dim3(NT), blk, 0, stream>>>(rois, PD1, PD2, Wg_w, Wg_b, ATT, INVp, n1b, n1p, PT);
    rel_mfma<<<dim3(NT / 64, 16), blk, 0, stream>>>(ATT, PVt, conv_b, INVp,
                                                    (float*)d_out, n1b, n1p, PT);
}

// Round 12
// 203.167 us; speedup vs baseline: 1.1068x; 1.1068x over previous
//
#include <hip/hip_runtime.h>

typedef unsigned short u16;
using short8  = __attribute__((ext_vector_type(8))) short;
using float4v = __attribute__((ext_vector_type(4))) float;

__device__ __forceinline__ u16 f2bf(float f) {
    union { float f; unsigned u; } v; v.f = f;
    unsigned r = (v.u + 0x7fff + ((v.u >> 16) & 1)) >> 16;
    return (u16)r;
}
__device__ __forceinline__ float bf2f(u16 h) {
    union { unsigned u; float f; } v; v.u = ((unsigned)h) << 16; return v.f;
}
// HW packed f32x2 -> bf16x2 (lo in low 16 bits). CDNA3+/gfx950.
__device__ __forceinline__ unsigned pkbf(float lo, float hi) {
    unsigned d;
    asm("v_cvt_pk_bf16_f32 %0, %1, %2" : "=v"(d) : "v"(lo), "v"(hi));
    return d;
}
// sin(2*pi*r): v_fract then hardware v_sin (input in revolutions).
__device__ __forceinline__ float sin_rev(float r) {
    float f, s;
    asm("v_fract_f32 %0, %1" : "=v"(f) : "v"(r));
    asm("v_sin_f32 %0, %1" : "=v"(s) : "v"(f));
    return s;
}
__device__ __forceinline__ void dma16(const void* g, void* l) {
    __builtin_amdgcn_global_load_lds((const __attribute__((address_space(1))) void*)g,
                                     (__attribute__((address_space(3))) void*)l, 16, 0, 0);
}

// ---------------------------------------------------------------------------
// merged f32 -> bf16 bulk convert for five tensors + PD precompute
// PD[p] = (pcx, pcy, log(pw), log(ph))
// ---------------------------------------------------------------------------
__device__ __forceinline__ void cvt4(const float* __restrict__ s, u16* __restrict__ o, int i) {
    float4 v = ((const float4*)s)[i];
    uint2 r; r.x = pkbf(v.x, v.y); r.y = pkbf(v.z, v.w);
    ((uint2*)o)[i] = r;
}

__global__ __launch_bounds__(256)
void cvt_all(const float* __restrict__ s0, const float* __restrict__ s1,
             const float* __restrict__ s2, const float* __restrict__ s3,
             const float* __restrict__ s4, const float* __restrict__ prois,
             u16* __restrict__ o0, u16* __restrict__ o1, u16* __restrict__ o2,
             u16* __restrict__ o3, u16* __restrict__ o4, float4* __restrict__ PD,
             int na4, int nb4, int nw4, int PT) {
    int i = blockIdx.x * 256 + threadIdx.x;
    if (i < na4) { cvt4(s0, o0, i); return; }
    i -= na4;
    if (i < nb4) { cvt4(s1, o1, i); return; }
    i -= nb4;
    if (i < nw4) { cvt4(s2, o2, i); return; }
    i -= nw4;
    if (i < nw4) { cvt4(s3, o3, i); return; }
    i -= nw4;
    if (i < nw4) { cvt4(s4, o4, i); return; }
    i -= nw4;
    if (i < PT) {
        const float* pr = prois + (size_t)i * 5;
        float pxmin = pr[1], pymin = pr[2], pxmax = pr[3], pymax = pr[4];
        PD[i] = make_float4(0.5f * (pxmin + pxmax), 0.5f * (pymin + pymax),
                            __logf(pxmax - pxmin + 1.0f), __logf(pymax - pymin + 1.0f));
    }
}

// ---------------------------------------------------------------------------
// proj: C[m,j] = sum_k A[m,k]*W[j,k] (+bias). z=0: Q, z=1: K, z=2: PV->PVt.
// Tile 128m x 64j, BK=64, grid (16j,16m,3) = 768 blocks (3/CU).
// ---------------------------------------------------------------------------
__global__ __launch_bounds__(256)
void proj_mfma(const u16* __restrict__ Ab, const u16* __restrict__ Pb,
               const u16* __restrict__ Wqb, const u16* __restrict__ Wkb,
               const u16* __restrict__ Cwb, const float* __restrict__ bq,
               const float* __restrict__ bk, u16* __restrict__ Qb,
               u16* __restrict__ Kb, u16* __restrict__ PVt, int PT) {
    __shared__ __align__(16) u16 As[128 * 64];
    __shared__ __align__(16) u16 Ws[64 * 64];
    __shared__ __align__(16) u16 Tr[128 * 68];

    const int z = blockIdx.z;
    const int m0 = blockIdx.y * 128, j0 = blockIdx.x * 64;
    const u16* A = (z == 0) ? Ab : Pb;
    const u16* W = (z == 0) ? Wqb : (z == 1 ? Wkb : Cwb);
    const int t = threadIdx.x;
    const int w = t >> 6, lane = t & 63;
    const int wm = w >> 1, wn = w & 1;
    const int lr = lane >> 3, lc = lane & 7, gch = lc ^ lr;
    const int fm = lane & 15, quad = lane >> 4;

    float4v zero4 = {0.f, 0.f, 0.f, 0.f};
    float4v acc[4][2];
#pragma unroll
    for (int i = 0; i < 4; ++i) { acc[i][0] = zero4; acc[i][1] = zero4; }

    for (int k0 = 0; k0 < 1024; k0 += 64) {
#pragma unroll
        for (int i = 0; i < 4; ++i) {
            int row = w * 32 + i * 8 + lr;
            dma16(A + (size_t)(m0 + row) * 1024 + k0 + gch * 8,
                  As + (w * 32 + i * 8) * 64 + lane * 8);
        }
#pragma unroll
        for (int i = 0; i < 2; ++i) {
            int row = w * 16 + i * 8 + lr;
            dma16(W + (size_t)(j0 + row) * 1024 + k0 + gch * 8,
                  Ws + (w * 16 + i * 8) * 64 + lane * 8);
        }
        __syncthreads();
#pragma unroll
        for (int ks = 0; ks < 2; ++ks) {
            int c = ks * 4 + quad;
            short8 af[4], bf[2];
#pragma unroll
            for (int i = 0; i < 4; ++i) {
                int ra = wm * 64 + i * 16 + fm;
                af[i] = *(const short8*)(As + ra * 64 + ((c ^ (ra & 7)) * 8));
            }
#pragma unroll
            for (int j = 0; j < 2; ++j) {
                int rb = wn * 32 + j * 16 + fm;
                bf[j] = *(const short8*)(Ws + rb * 64 + ((c ^ (rb & 7)) * 8));
            }
#pragma unroll
            for (int i = 0; i < 4; ++i)
#pragma unroll
                for (int j = 0; j < 2; ++j)
                    acc[i][j] = __builtin_amdgcn_mfma_f32_16x16x32_bf16(af[i], bf[j], acc[i][j], 0, 0, 0);
        }
        __syncthreads();
    }

    if (z < 2) {
        u16* O = z ? Kb : Qb;
        const float* bias = z ? bk : bq;
#pragma unroll
        for (int j = 0; j < 2; ++j) {
            int jl = wn * 32 + j * 16 + fm;
            float bb = bias[j0 + jl];
#pragma unroll
            for (int i = 0; i < 4; ++i) {
                int mlb = wm * 64 + i * 16 + quad * 4;
#pragma unroll
                for (int r = 0; r < 4; ++r)
                    Tr[(mlb + r) * 68 + jl] = f2bf(acc[i][j][r] + bb);
            }
        }
        __syncthreads();
#pragma unroll
        for (int i2 = 0; i2 < 4; ++i2) {
            int f = i2 * 2048 + t * 8;
            int ml = f >> 6, jl = f & 63;
            union { uint2 u2[2]; short8 s8; } uu;
            uu.u2[0] = *(const uint2*)(Tr + ml * 68 + jl);
            uu.u2[1] = *(const uint2*)(Tr + ml * 68 + jl + 4);
            *(short8*)(O + (size_t)(m0 + ml) * 1024 + j0 + jl) = uu.s8;
        }
    } else {
#pragma unroll
        for (int j = 0; j < 2; ++j) {
            int jl = wn * 32 + j * 16 + fm;
#pragma unroll
            for (int i = 0; i < 4; ++i) {
                int mlb = wm * 64 + i * 16 + quad * 4;
                uint2 pk;
                pk.x = pkbf(acc[i][j][0], acc[i][j][1]);
                pk.y = pkbf(acc[i][j][2], acc[i][j][3]);
                *(uint2*)(Tr + jl * 136 + mlb) = pk;
            }
        }
        __syncthreads();
#pragma unroll
        for (int i2 = 0; i2 < 4; ++i2) {
            int f = i2 * 2048 + t * 8;
            int jl = f >> 7, ml = f & 127;
            union { uint2 u2[2]; short8 s8; } uu;
            uu.u2[0] = *(const uint2*)(Tr + jl * 136 + ml);
            uu.u2[1] = *(const uint2*)(Tr + jl * 136 + ml + 4);
            *(short8*)(PVt + (size_t)(j0 + jl) * PT + m0 + ml) = uu.s8;
        }
    }
}

// ---------------------------------------------------------------------------
// att: ATT[n][g][p] = exp((1/16) sum_d Q*K)  -- exp folded in, bf16 out.
// ---------------------------------------------------------------------------
__global__ __launch_bounds__(256)
void att_mfma(const u16* __restrict__ Qb, const u16* __restrict__ Kb,
              u16* __restrict__ ATT, const int* __restrict__ n1b_p,
              const int* __restrict__ n1p_p, int PT) {
    __shared__ __align__(16) u16 Qs[128 * 64];
    __shared__ __align__(16) u16 Ks[128 * 64];
    __shared__ __align__(16) u16 Tr[128 * 130];

    const int g = blockIdx.z;
    const int n0 = blockIdx.y * 128, pl0 = blockIdx.x * 128;
    const int n1b = *n1b_p, n1p = *n1p_p;
    const int hh = (n0 >= n1b) ? 1 : 0;
    const int p0 = hh ? n1p : 0;
    const int Ph = hh ? (PT - n1p) : n1p;
    if (pl0 >= Ph) return;
    const int t = threadIdx.x;
    const int w = t >> 6, lane = t & 63;
    const int wm = w >> 1, wn = w & 1;
    const int lr = lane >> 3, lc = lane & 7, gch = lc ^ lr;
    const int fm = lane & 15, quad = lane >> 4;

    float4v zero4 = {0.f, 0.f, 0.f, 0.f};
    float4v acc[4][4];
#pragma unroll
    for (int i = 0; i < 4; ++i)
#pragma unroll
        for (int j = 0; j < 4; ++j) acc[i][j] = zero4;

#pragma unroll
    for (int i = 0; i < 4; ++i) {
        int row = w * 32 + i * 8 + lr;
        dma16(Qb + (size_t)(n0 + row) * 1024 + g * 64 + gch * 8,
              Qs + (w * 32 + i * 8) * 64 + lane * 8);
        dma16(Kb + (size_t)(p0 + pl0 + row) * 1024 + g * 64 + gch * 8,
              Ks + (w * 32 + i * 8) * 64 + lane * 8);
    }
    __syncthreads();
#pragma unroll
    for (int ks = 0; ks < 2; ++ks) {
        int c = ks * 4 + quad;
        short8 af[4], bf[4];
#pragma unroll
        for (int i = 0; i < 4; ++i) {
            int ra = wm * 64 + i * 16 + fm;
            af[i] = *(const short8*)(Qs + ra * 64 + ((c ^ (ra & 7)) * 8));
            int rb = wn * 64 + i * 16 + fm;
            bf[i] = *(const short8*)(Ks + rb * 64 + ((c ^ (rb & 7)) * 8));
        }
#pragma unroll
        for (int i = 0; i < 4; ++i)
#pragma unroll
            for (int j = 0; j < 4; ++j)
                acc[i][j] = __builtin_amdgcn_mfma_f32_16x16x32_bf16(af[i], bf[j], acc[i][j], 0, 0, 0);
    }
#pragma unroll
    for (int j = 0; j < 4; ++j) {
        int pl = wn * 64 + j * 16 + fm;
#pragma unroll
        for (int i = 0; i < 4; ++i)
#pragma unroll
            for (int r = 0; r < 4; ++r) {
                int nl = wm * 64 + i * 16 + quad * 4 + r;
                Tr[nl * 130 + pl] = f2bf(__expf(acc[i][j][r] * 0.0625f));
            }
    }
    __syncthreads();
#pragma unroll
    for (int i = 0; i < 8; ++i) {
        int f = i * 2048 + t * 8;
        int nl = f >> 7, pl = f & 127;
        short8 v = *(const short8*)(Tr + nl * 130 + pl);
        *(short8*)(ATT + ((size_t)(n0 + nl) * 16 + g) * 1024 + pl0 + pl) = v;
    }
}

// ---------------------------------------------------------------------------
// softmax (R7 config): w[n,g,p] = max(pf,1e-6)*eatt, UNNORMALIZED, in-place
// RMW in D-layout with load/store adjacent in time (keeps line resident).
// One-ahead prefetch of PD + eatt. INV[n][g] = 1/sum_p w.
// ---------------------------------------------------------------------------
__global__ __launch_bounds__(256)
void softmax_fused(const float* __restrict__ rois, const float4* __restrict__ PD,
                   const float* __restrict__ Wg_w, const float* __restrict__ Wg_b,
                   u16* __restrict__ ATT, float* __restrict__ INV,
                   const int* __restrict__ n1b_p, const int* __restrict__ n1p_p, int PT) {
    __shared__ float redl[4][16];

    const int n = blockIdx.x, t = threadIdx.x;
    const int w = t >> 6, lane = t & 63;
    const int fm = lane & 15, quad = lane >> 4;
    const int n1b = *n1b_p, n1p = *n1p_p;
    const int hh = (n >= n1b) ? 1 : 0;
    const int p0 = hh ? n1p : 0;
    const int Ph = hh ? (PT - n1p) : n1p;   // 1024

    // n-box (block-uniform)
    float xmin = rois[n * 5 + 1], ymin = rois[n * 5 + 2];
    float xmax = rois[n * 5 + 3], ymax = rois[n * 5 + 4];
    float bw = xmax - xmin + 1.0f, bh = ymax - ymin + 1.0f;
    float cx = 0.5f * (xmin + xmax), cy = 0.5f * (ymin + ymax);

    const int jA = quad >> 1, trig = quad & 1;
    float cA   = (jA == 0) ? cx : cy;
    float invA = (jA == 0) ? (1.0f / bw) : (1.0f / bh);
    float lB   = (jA == 0) ? __logf(bw) : __logf(bh);
    float toff = trig ? 0.25f : 0.0f;

    // Wg b-fragments in registers; bias folded into acc init
    const int g_ = fm;
    short8 b1, b2;
    {
        const float* w1 = Wg_w + g_ * 64 + quad * 8;
        const float* w2 = Wg_w + g_ * 64 + 32 + quad * 8;
        unsigned* p1 = (unsigned*)&b1;
        unsigned* p2 = (unsigned*)&b2;
#pragma unroll
        for (int kk = 0; kk < 4; ++kk) {
            p1[kk] = pkbf(w1[2 * kk], w1[2 * kk + 1]);
            p2[kk] = pkbf(w2[2 * kk], w2[2 * kk + 1]);
        }
    }
    float wgb = Wg_b[g_];

    const float inv_em[8] = {1.0f, 0.4216965034f, 0.1778279410f, 0.0749894209f,
                             0.0316227766f, 0.0133352143f, 0.0056234133f, 0.0023713737f};
    const float REV = 15.91549431f;  // 100 / (2*pi)
    const int prange = Ph >> 2;      // p per wave (256)
    const int pb0 = w * prange;
    float ssum = 0.0f;
    u16* rowp = ATT + ((size_t)n * 16 + g_) * 1024;  // row for g = fm

    // software pipeline: prefetch PD + eatt one tile ahead
    float4 pd_c = PD[p0 + pb0 + fm];
    ushort4 ea_c = *(const ushort4*)(rowp + pb0 + quad * 4);

#pragma unroll 2
    for (int pt = 0; pt < 16; ++pt) {
        int pbase = pb0 + pt * 16;
        float4 pd_n;
        ushort4 ea_n;
        if (pt < 15) {
            pd_n = PD[p0 + pbase + 16 + fm];
            ea_n = *(const ushort4*)(rowp + pbase + 16 + quad * 4);
        }
        float pc = (jA == 0) ? pd_c.x : pd_c.y;
        float lp = (jA == 0) ? pd_c.z : pd_c.w;
        float posA = __logf(fmaxf(fabsf(cA - pc) * invA, 0.001f));
        float posB = lp - lB;
        float br1 = posA * REV, br2 = posB * REV;
        float e1[8], e2[8];
#pragma unroll
        for (int k = 0; k < 8; ++k) {
            e1[k] = sin_rev(fmaf(br1, inv_em[k], toff));
            e2[k] = sin_rev(fmaf(br2, inv_em[k], toff));
        }
        short8 a1, a2;
        unsigned* pa1 = (unsigned*)&a1;
        unsigned* pa2 = (unsigned*)&a2;
#pragma unroll
        for (int kk = 0; kk < 4; ++kk) {
            pa1[kk] = pkbf(e1[2 * kk], e1[2 * kk + 1]);
            pa2[kk] = pkbf(e2[2 * kk], e2[2 * kk + 1]);
        }
        float4v acc = {wgb, wgb, wgb, wgb};
        acc = __builtin_amdgcn_mfma_f32_16x16x32_bf16(a1, b1, acc, 0, 0, 0);
        acc = __builtin_amdgcn_mfma_f32_16x16x32_bf16(a2, b2, acc, 0, 0, 0);

        float w0  = fmaxf(acc[0], 1e-6f) * bf2f(ea_c.x);
        float w1v = fmaxf(acc[1], 1e-6f) * bf2f(ea_c.y);
        float w2v = fmaxf(acc[2], 1e-6f) * bf2f(ea_c.z);
        float w3v = fmaxf(acc[3], 1e-6f) * bf2f(ea_c.w);
        ssum += (w0 + w1v) + (w2v + w3v);
        uint2 wp; wp.x = pkbf(w0, w1v); wp.y = pkbf(w2v, w3v);
        *(uint2*)(rowp + pbase + quad * 4) = wp;

        pd_c = pd_n;
        ea_c = ea_n;
    }

    ssum += __shfl_xor(ssum, 16, 64);
    ssum += __shfl_xor(ssum, 32, 64);
    if (lane < 16) redl[w][lane] = ssum;
    __syncthreads();
    if (t < 16)
        INV[(size_t)n * 16 + t] = 1.0f / (redl[0][t] + redl[1][t] + redl[2][t] + redl[3][t]);
}

// ---------------------------------------------------------------------------
// rel: OUT[n, g*64+o] = (sum_p w[n,g,p]*PVt[g*64+o, p0+p]) * INV[n,g] + conv_b
// Tile 64n x 64o, BK=128 (8 K-iters, 16 MFMA/barrier), grid (NT/64, 16).
// LDS 32 KB -> 5 blocks/CU capacity; XOR swizzle over row&15 (2-way = free).
// ---------------------------------------------------------------------------
__global__ __launch_bounds__(256)
void rel_mfma(const u16* __restrict__ SM, const u16* __restrict__ PVt,
              const float* __restrict__ conv_b, const float* __restrict__ INV,
              float* __restrict__ OUT, const int* __restrict__ n1b_p,
              const int* __restrict__ n1p_p, int PT) {
    __shared__ __align__(16) u16 As[64 * 128];
    __shared__ __align__(16) u16 Bs[64 * 128];

    const int n0 = blockIdx.x * 64, g = blockIdx.y;
    const int n1b = *n1b_p, n1p = *n1p_p;
    const int hh = (n0 >= n1b) ? 1 : 0;
    const int p0 = hh ? n1p : 0;
    const int Ph = hh ? (PT - n1p) : n1p;
    const int t = threadIdx.x;
    const int w = t >> 6, lane = t & 63;
    const int wm = w >> 1, wn = w & 1;
    const int fm = lane & 15, quad = lane >> 4;

    // staging decomposition: flat = i*256 + t; row = flat>>4, lc = flat&15
    const int srow = (w * 64 + lane) >> 4;     // row contribution per round
    const int slc  = lane & 15;
    // note: flat>>4 = i*16 + (w*64+lane)>>4 since 256/16 = 16 rows per round

    float4v zero4 = {0.f, 0.f, 0.f, 0.f};
    float4v acc[2][2];
#pragma unroll
    for (int i = 0; i < 2; ++i) { acc[i][0] = zero4; acc[i][1] = zero4; }

    for (int k0 = 0; k0 < Ph; k0 += 128) {
#pragma unroll
        for (int i = 0; i < 4; ++i) {
            int row = i * 16 + srow;
            int gch = slc ^ (row & 15);
            dma16(SM + ((size_t)(n0 + row) * 16 + g) * 1024 + k0 + gch * 8,
                  As + (i * 16 + (w * 64 >> 4) * 0 + row - srow + srow) * 0 +  // (kept simple below)
                  (i * 256 + t) * 8);
        }
#pragma unroll
        for (int i = 0; i < 4; ++i) {
            int row = i * 16 + srow;
            int gch = slc ^ (row & 15);
            dma16(PVt + (size_t)(g * 64 + row) * PT + p0 + k0 + gch * 8,
                  Bs + (i * 256 + t) * 8);
        }
        __syncthreads();
#pragma unroll
        for (int ks = 0; ks < 4; ++ks) {
            int c = ks * 4 + quad;
            short8 af[2], bf[2];
#pragma unroll
            for (int i = 0; i < 2; ++i) {
                int ra = wm * 32 + i * 16 + fm;
                af[i] = *(const short8*)(As + ra * 128 + ((c ^ (ra & 15)) * 8));
                int rb = wn * 32 + i * 16 + fm;
                bf[i] = *(const short8*)(Bs + rb * 128 + ((c ^ (rb & 15)) * 8));
            }
#pragma unroll
            for (int i = 0; i < 2; ++i)
#pragma unroll
                for (int j = 0; j < 2; ++j)
                    acc[i][j] = __builtin_amdgcn_mfma_f32_16x16x32_bf16(af[i], bf[j], acc[i][j], 0, 0, 0);
        }
        __syncthreads();
    }
    float bb[2];
    bb[0] = conv_b[g * 64 + wn * 32 + fm];
    bb[1] = conv_b[g * 64 + wn * 32 + 16 + fm];
#pragma unroll
    for (int i = 0; i < 2; ++i)
#pragma unroll
        for (int r = 0; r < 4; ++r) {
            int nn = n0 + wm * 32 + i * 16 + quad * 4 + r;
            float iv = INV[(size_t)nn * 16 + g];
#pragma unroll
            for (int j = 0; j < 2; ++j) {
                int o = wn * 32 + j * 16 + fm;
                OUT[(size_t)nn * 1024 + g * 64 + o] = acc[i][j][r] * iv + bb[j];
            }
        }
}

extern "C" void kernel_launch(void* const* d_in, const int* in_sizes, int n_in,
                              void* d_out, int out_size, void* d_ws, size_t ws_size,
                              hipStream_t stream) {
    const float* rois   = (const float*)d_in[0];
    const float* prois  = (const float*)d_in[1];
    const float* bfeat  = (const float*)d_in[2];
    const float* pfeat  = (const float*)d_in[3];
    const float* Wg_w   = (const float*)d_in[4];
    const float* Wg_b   = (const float*)d_in[5];
    const float* Wq_w   = (const float*)d_in[6];
    const float* Wq_b   = (const float*)d_in[7];
    const float* Wk_w   = (const float*)d_in[8];
    const float* Wk_b   = (const float*)d_in[9];
    const float* conv_w = (const float*)d_in[10];
    const float* conv_b = (const float*)d_in[11];
    const int*   n1b    = (const int*)d_in[12];
    const int*   n1p    = (const int*)d_in[13];

    const int NT = in_sizes[2] / 1024;  // 2048
    const int PT = in_sizes[3] / 1024;  // 2048

    u16* ATT = (u16*)d_ws;                          // [NT][16][1024]
    u16* Qb  = ATT + (size_t)NT * 16 * 1024;        // [NT][1024]
    u16* Kb  = Qb + (size_t)NT * 1024;              // [PT][1024]
    u16* PVt = Kb + (size_t)PT * 1024;              // [1024][PT]
    float* INVp = (float*)(PVt + (size_t)1024 * PT);   // [NT][16]
    float4* PD  = (float4*)(INVp + (size_t)NT * 16);   // [PT]
    u16* Ab  = ATT;                                 // aliases (consumed by proj)
    u16* Pb  = Ab + (size_t)NT * 1024;
    u16* Wqb = Pb + (size_t)PT * 1024;
    u16* Wkb = Wqb + 1024 * 1024;
    u16* Cwb = Wkb + 1024 * 1024;

    dim3 blk(256);
    int nf4 = NT * 1024 / 4, pf4 = PT * 1024 / 4, wf4 = 1024 * 1024 / 4;
    int tot = nf4 + pf4 + 3 * wf4 + PT;
    cvt_all<<<dim3((tot + 255) / 256), blk, 0, stream>>>(
        bfeat, pfeat, Wq_w, Wk_w, conv_w, prois, Ab, Pb, Wqb, Wkb, Cwb, PD,
        nf4, pf4, wf4, PT);

    proj_mfma<<<dim3(16, NT / 128, 3), blk, 0, stream>>>(Ab, Pb, Wqb, Wkb, Cwb,
                                                         Wq_b, Wk_b, Qb, Kb, PVt, PT);
    att_mfma<<<dim3(PT / 128, NT / 128, 16), blk, 0, stream>>>(Qb, Kb, ATT, n1b, n1p, PT);
    softmax_fused<<<dim3(NT), blk, 0, stream>>>(rois, PD, Wg_w, Wg_b, ATT, INVp, n1b, n1p, PT);
    rel_mfma<<<dim3(NT / 64, 16), blk, 0, stream>>>(ATT, PVt, conv_b, INVp,
                                                    (float*)d_out, n1b, n1p, PT);
}